// Round 12
// baseline (2296.438 us; speedup 1.0000x reference)
//
#include <hip/hip_runtime.h>
#include <stdint.h>

typedef unsigned long long u64;
typedef unsigned int u32;
typedef __attribute__((ext_vector_type(2))) unsigned long long u64x2;

#define NPTS    131072
#define NBATCH  16
#define NSAMP   1024
#define SUBS    16                 // blocks per batch
#define THREADS 256
#define PPT     32                 // points per thread

// Packed word: [ tag:10 (bits 49..58) | key:32 (17..48) | (131071-idx):17 (0..16) ]
// key = 0 for masked-out (cand == -1), else float_bits(val)+1 (monotone for val >= 0).
// TAG IN HIGH BITS => round it's candidates always beat any earlier round's value,
// so a single accumulating atomic-max cell needs no per-round reset.
//
// r12 structure: per batch ONE LLC line: cell[0]=val (atomic umax), cell[1]=cnt
// (atomic add, monotone; round it complete <=> cnt == 16*it).
// Publisher (per block): blk = intra-block max; old = fetch_max(val, blk) RETURNING
// (old's arrival proves the RMW executed at the TCC); s_waitcnt; fetch_add(cnt,1).
// Poller: one 16B snapshot of the line. Since val & cnt share one line, the
// snapshot is a single read in that line's serial op order; cnt==16*it implies all
// 16 adds precede the read, each add follows its own max => val is final. No
//16-slot freshness race, no 16->1 reduce, no parity buffers.

__device__ __forceinline__ u64 ld_agent(const u64* p) {
    return __hip_atomic_load(p, __ATOMIC_RELAXED, __HIP_MEMORY_SCOPE_AGENT);
}
// 16B line snapshot, L1/L2-bypassing (LLC-coherent). Same asm style ran fine in r8.
__device__ __forceinline__ u64x2 snap16(const u64* p) {
    u64x2 v;
    asm volatile("global_load_dwordx4 %0, %1, off sc0 sc1\n\ts_waitcnt vmcnt(0)"
                 : "=v"(v) : "v"(p) : "memory");
    return v;
}

__global__ __launch_bounds__(THREADS, 1)
void fps_kernel(const float* __restrict__ x, float* __restrict__ y, u64* __restrict__ ws)
{
    const int bid   = blockIdx.x;
    const int batch = bid & (NBATCH - 1);
    const int sub   = bid >> 4;
    const int tid   = threadIdx.x;
    const int lane  = tid & 63;
    const int wv    = tid >> 6;

    const float* __restrict__ xb = x + (size_t)batch * (NPTS * 3);
    const int gbase = sub * 8192 + wv * 2048;

    // register-resident points + running min distance (static indexing only)
    float px_[PPT], py_[PPT], pz_[PPT], t_[PPT];
#pragma unroll
    for (int k = 0; k < PPT; ++k) {
        const int g = gbase + k * 64 + lane;
        const float a = xb[3 * g + 0];
        const float b = xb[3 * g + 1];
        const float c = xb[3 * g + 2];
        px_[k] = a; py_[k] = b; pz_[k] = c;
        // exactly as reference: ((a*a + b*b) + c*c), no FMA contraction
        const float mag = __fadd_rn(__fadd_rn(__fmul_rn(a, a), __fmul_rn(b, b)), __fmul_rn(c, c));
        t_[k] = (mag > 1e-3f) ? 1e10f : -1.0f;   // masked-out: cand == -1 forever
    }

    __shared__ u64 s_red[2][4];

    u64* const cell = ws + (size_t)batch * 128;   // 1024B stride; [0]=val, [1]=cnt

    float cpx = xb[0], cpy = xb[1], cpz = xb[2];   // first pick is always index 0
    if (sub == 0 && tid == 0) {
        float* yo = y + (size_t)batch * (NSAMP * 3);
        yo[0] = cpx; yo[1] = cpy; yo[2] = cpz;
    }

    for (int it = 1; it < NSAMP; ++it) {
        // ---- update temps against current point, thread-local argmax ----
        float bv = -2.0f;
        int   bk = 0;
#pragma unroll
        for (int k = 0; k < PPT; ++k) {
            const float dx = __fsub_rn(px_[k], cpx);
            const float dy = __fsub_rn(py_[k], cpy);
            const float dz = __fsub_rn(pz_[k], cpz);
            const float d  = __fadd_rn(__fadd_rn(__fmul_rn(dx, dx), __fmul_rn(dy, dy)),
                                       __fmul_rn(dz, dz));
            const float tn = fminf(t_[k], d);
            t_[k] = tn;
            if (tn > bv) { bv = tn; bk = k; }   // strict > keeps smallest k
        }
        const int gidx = gbase + bk * 64 + lane;
        const u32 key  = (bv < 0.0f) ? 0u : (__float_as_uint(bv) + 1u);
        u64 packed = ((u64)(u32)it << 49) | ((u64)key << 17) | (u32)(131071 - gidx);

        // ---- wave reduce (max of packed, first-max tiebreak) ----
#pragma unroll
        for (int off = 32; off; off >>= 1) {
            const u64 o = __shfl_xor(packed, off);
            if (o > packed) packed = o;
        }

        const int par = it & 1;
        if (lane == 0) s_red[par][wv] = packed;   // parity-buffered: no cross-round overwrite
        __syncthreads();                          // the ONLY barrier per round

        if (wv == 0 && lane == 0) {
            u64 blk = s_red[par][0];
            if (s_red[par][1] > blk) blk = s_red[par][1];
            if (s_red[par][2] > blk) blk = s_red[par][2];
            if (s_red[par][3] > blk) blk = s_red[par][3];
            // returning max: old's arrival proves execution at the TCC ...
            u64 old = __hip_atomic_fetch_max(cell, blk, __ATOMIC_RELAXED,
                                             __HIP_MEMORY_SCOPE_AGENT);
            asm volatile("s_waitcnt vmcnt(0)" :: "v"(old) : "memory");
            // ... so cnt can only tick after this block's max landed
            __hip_atomic_fetch_add(cell + 1, 1ull, __ATOMIC_RELAXED,
                                   __HIP_MEMORY_SCOPE_AGENT);
        }

        // ---- all waves poll ONE line; speculative coord prefetch while waiting ----
        const u64 target = 16ull * (u64)it;
        int   spec = -1;
        float wx = 0.0f, wy = 0.0f, wz = 0.0f;
        __builtin_amdgcn_s_sleep(8);              // ~512cy: land near publish completion
        for (;;) {
            const u64x2 s = snap16(cell);         // one coherent line read: {val, cnt}
            const u64 v = s.x;
            if ((u32)(v >> 49) == (u32)it) {      // current-round leader visible ...
                const int ci = 131071 - (int)(v & 0x1FFFF);
                if (ci != spec) {                 // ... prefetch its coords (cached, read-only)
                    spec = ci;
                    wx = xb[3 * ci + 0]; wy = xb[3 * ci + 1]; wz = xb[3 * ci + 2];
                }
            }
            if (s.y >= target) break;             // all 16 landed => v is final (proof above)
            __builtin_amdgcn_s_sleep(2);          // ~128cy backoff between re-checks
        }
        cpx = wx; cpy = wy; cpz = wz;             // last snapshot updated spec == winner
        if (sub == 0 && wv == 0 && lane == 0) {
            float* yo = y + ((size_t)batch * NSAMP + it) * 3;
            yo[0] = cpx; yo[1] = cpy; yo[2] = cpz;
        }
    }
}

extern "C" void kernel_launch(void* const* d_in, const int* in_sizes, int n_in,
                              void* d_out, int out_size, void* d_ws, size_t ws_size,
                              hipStream_t stream) {
    const float* x = (const float*)d_in[0];
    float* y       = (float*)d_out;
    u64* ws        = (u64*)d_ws;   // 16 batches * 1024B = 16 KiB

    // zero val+cnt every call (in-graph, ordered before the kernel in the graph):
    // cnt restarts at 0 (targets are 16*it), val restarts at 0 (any tag>=1 beats it).
    hipMemsetAsync(d_ws, 0, (size_t)(NBATCH * 1024), stream);

    void* args[] = { (void*)&x, (void*)&y, (void*)&ws };
    hipLaunchCooperativeKernel((void*)fps_kernel,
                               dim3(NBATCH * SUBS), dim3(THREADS),
                               args, 0, stream);
}

// Round 13
// 1971.298 us; speedup vs baseline: 1.1649x; 1.1649x over previous
//
#include <hip/hip_runtime.h>
#include <stdint.h>

typedef unsigned long long u64;
typedef unsigned int u32;

#define NPTS    131072
#define NBATCH  16
#define NSAMP   1024
#define SUBS    16                 // blocks per batch
#define THREADS 256
#define PPT     32                 // points per thread

// Packed word: [ tag:10 (bits 49..58) | key:32 (17..48) | (131071-idx):17 (0..16) ]
// key = 0 for masked-out (cand == -1), else float_bits(val)+1 (monotone for val >= 0).
// Max of packed (same tag) == reference first-max argmax (smaller index wins ties).
//
// Layout = r9's proven one: per-batch 32 u64 at 1024B stride; parity p ->
// slots [p*16 .. p*16+15] (ONE 128B line per parity). One plain agent store
// per block per round; pollers validate the embedded tag (self-contained).
//
// r13 change vs r9: PIPELINED POLLING. r9's poll period was a full load RT
// (~1000cy) because each check waited vmcnt(0) on its own load -> discovery
// quantized to ~1100cy, and the last-discovering block convoys the next round.
// Here each wave keeps 4 slot-loads outstanding, spaced ~160cy, checked
// oldest-first; the compiler's partial vmcnt waits (G7/m131) make sampling
// granularity = issue spacing, not RT. All polls stay on the same hot
// LLC-resident line (r9/r10 evidence: hot-line re-reads don't touch HBM).

__device__ __forceinline__ u64 ld_agent(const u64* p) {
    return __hip_atomic_load(p, __ATOMIC_RELAXED, __HIP_MEMORY_SCOPE_AGENT);
}
__device__ __forceinline__ void st_agent(u64* p, u64 v) {
    __hip_atomic_store(p, v, __ATOMIC_RELAXED, __HIP_MEMORY_SCOPE_AGENT);
}

__global__ __launch_bounds__(THREADS, 1)
void fps_kernel(const float* __restrict__ x, float* __restrict__ y, u64* __restrict__ ws)
{
    const int bid   = blockIdx.x;
    const int batch = bid & (NBATCH - 1);
    const int sub   = bid >> 4;
    const int tid   = threadIdx.x;
    const int lane  = tid & 63;
    const int wv    = tid >> 6;

    const float* __restrict__ xb = x + (size_t)batch * (NPTS * 3);
    const int gbase = sub * 8192 + wv * 2048;

    // register-resident points + running min distance (static indexing only)
    float px_[PPT], py_[PPT], pz_[PPT], t_[PPT];
#pragma unroll
    for (int k = 0; k < PPT; ++k) {
        const int g = gbase + k * 64 + lane;
        const float a = xb[3 * g + 0];
        const float b = xb[3 * g + 1];
        const float c = xb[3 * g + 2];
        px_[k] = a; py_[k] = b; pz_[k] = c;
        // exactly as reference: ((a*a + b*b) + c*c), no FMA contraction
        const float mag = __fadd_rn(__fadd_rn(__fmul_rn(a, a), __fmul_rn(b, b)), __fmul_rn(c, c));
        t_[k] = (mag > 1e-3f) ? 1e10f : -1.0f;   // masked-out: cand == -1 forever
    }

    __shared__ u64 s_red[2][4];

    u64* const slots = ws + (size_t)batch * 128;   // 1024B per batch (u64 units)

    float cpx = xb[0], cpy = xb[1], cpz = xb[2];   // first pick is always index 0
    if (sub == 0 && tid == 0) {
        float* yo = y + (size_t)batch * (NSAMP * 3);
        yo[0] = cpx; yo[1] = cpy; yo[2] = cpz;
    }

    for (int it = 1; it < NSAMP; ++it) {
        // ---- update temps against current point, thread-local argmax ----
        float bv = -2.0f;
        int   bk = 0;
#pragma unroll
        for (int k = 0; k < PPT; ++k) {
            const float dx = __fsub_rn(px_[k], cpx);
            const float dy = __fsub_rn(py_[k], cpy);
            const float dz = __fsub_rn(pz_[k], cpz);
            const float d  = __fadd_rn(__fadd_rn(__fmul_rn(dx, dx), __fmul_rn(dy, dy)),
                                       __fmul_rn(dz, dz));
            const float tn = fminf(t_[k], d);
            t_[k] = tn;
            if (tn > bv) { bv = tn; bk = k; }   // strict > keeps smallest k
        }
        const int gidx = gbase + bk * 64 + lane;
        const u32 key  = (bv < 0.0f) ? 0u : (__float_as_uint(bv) + 1u);
        u64 packed = ((u64)(u32)it << 49) | ((u64)key << 17) | (u32)(131071 - gidx);

        // ---- wave reduce (max of packed, first-max tiebreak) ----
#pragma unroll
        for (int off = 32; off; off >>= 1) {
            const u64 o = __shfl_xor(packed, off);
            if (o > packed) packed = o;
        }

        const int par = it & 1;
        if (lane == 0) s_red[par][wv] = packed;   // parity-buffered: no cross-round overwrite
        __syncthreads();                          // the ONLY barrier per round

        if (wv == 0 && lane == 0) {
            u64 blk = s_red[par][0];
            if (s_red[par][1] > blk) blk = s_red[par][1];
            if (s_red[par][2] > blk) blk = s_red[par][2];
            if (s_red[par][3] > blk) blk = s_red[par][3];
            st_agent(slots + par * SUBS + sub, blk);
        }

        // ---- pipelined poll: 4 outstanding loads, ~160cy sampling granularity.
        //      All 64 lanes read slot (lane&15) -> one hot 128B line. ----
        const u32 tag = (u32)it;
        u64* const sp = slots + par * SUBS + (lane & 15);
        __builtin_amdgcn_s_sleep(4);              // ~256cy: skip the certainly-stale window
        u64 a0 = ld_agent(sp); __builtin_amdgcn_s_sleep(2);
        u64 a1 = ld_agent(sp); __builtin_amdgcn_s_sleep(2);
        u64 a2 = ld_agent(sp); __builtin_amdgcn_s_sleep(2);
        u64 a3 = ld_agent(sp);
        u64 v;
        for (;;) {
            if (__all((int)((u32)(a0 >> 49) == tag))) { v = a0; break; }   // waits vmcnt(3)
            a0 = ld_agent(sp); __builtin_amdgcn_s_sleep(2);
            if (__all((int)((u32)(a1 >> 49) == tag))) { v = a1; break; }
            a1 = ld_agent(sp); __builtin_amdgcn_s_sleep(2);
            if (__all((int)((u32)(a2 >> 49) == tag))) { v = a2; break; }
            a2 = ld_agent(sp); __builtin_amdgcn_s_sleep(2);
            if (__all((int)((u32)(a3 >> 49) == tag))) { v = a3; break; }
            a3 = ld_agent(sp); __builtin_amdgcn_s_sleep(2);
        }
        // ---- reduce metas within 16-lane groups (every group holds all 16) ----
#pragma unroll
        for (int off = 8; off; off >>= 1) {
            const u64 o = __shfl_xor(v, off);
            if (o > v) v = o;
        }
        const u64 win  = __shfl(v, 0);
        const int widx = 131071 - (int)(win & 0x1FFFF);
        // all 64 lanes load the same 12B -> one line, broadcast-coalesced, 1 RT
        cpx = xb[3 * widx + 0];
        cpy = xb[3 * widx + 1];
        cpz = xb[3 * widx + 2];
        if (sub == 0 && wv == 0 && lane == 0) {
            float* yo = y + ((size_t)batch * NSAMP + it) * 3;
            yo[0] = cpx; yo[1] = cpy; yo[2] = cpz;
        }
    }
}

extern "C" void kernel_launch(void* const* d_in, const int* in_sizes, int n_in,
                              void* d_out, int out_size, void* d_ws, size_t ws_size,
                              hipStream_t stream) {
    const float* x = (const float*)d_in[0];
    float* y       = (float*)d_out;
    u64* ws        = (u64*)d_ws;   // 16 batches * 1024B = 16 KiB

    // zero all slot words every call (in-graph). Tags used are 1..1023; stale
    // content (zeros, 0xAA poison, previous replay's tags overwritten here)
    // can never spuriously satisfy a round's tag check.
    hipMemsetAsync(d_ws, 0, (size_t)(NBATCH * 1024), stream);

    void* args[] = { (void*)&x, (void*)&y, (void*)&ws };
    hipLaunchCooperativeKernel((void*)fps_kernel,
                               dim3(NBATCH * SUBS), dim3(THREADS),
                               args, 0, stream);
}